// Round 2
// baseline (248.534 us; speedup 1.0000x reference)
//
#include <hip/hip_runtime.h>

// AccumulatorLIF: I[t] = exp(-1/2)*I[t-1] + x[t]; out = sigmoid(4*(I-0.5))
// x: (T=1024, B=32, F=1024) fp32. Memory-bound: 256 MiB ideal traffic.
//
// Parallelization: chunk T into LCHUNK-long pieces; each chunk warm-starts
// KHALO steps early from I=0. decay^32 = e^-16 ~ 1.1e-7 -> truncation error
// ~8e-7 absmax, vs threshold 2e-2. Each thread owns a float4 along F for one
// chunk: coalesced 16B/lane loads/stores, 8 waves/CU.
//
// Use a native ext_vector float4 (f32x4): __builtin_nontemporal_store rejects
// HIP's class-type float4.

#define T_DIM   1024
#define B_DIM   32
#define F_DIM   1024
#define LCHUNK  64
#define KHALO   32
#define F4_DIM  (F_DIM / 4)          // 256 float4 per (t,b) row
#define SEQ4    (B_DIM * F4_DIM)     // 8192 float4 per time step
#define NCHUNK  (T_DIM / LCHUNK)     // 16

typedef float f32x4 __attribute__((ext_vector_type(4)));

__device__ __forceinline__ float spike1(float I) {
    // sigmoid(4*(I-0.5)) = 1 / (1 + exp(-4*(I-0.5)))
    float z = fmaf(-4.0f, I, 2.0f);          // -4*(I-0.5)
    float e = __expf(z);                      // fast v_exp path
    return __builtin_amdgcn_rcpf(1.0f + e);   // v_rcp_f32, ~1e-6 rel err
}

__device__ __forceinline__ f32x4 spike4(f32x4 I) {
    f32x4 r;
    r.x = spike1(I.x); r.y = spike1(I.y); r.z = spike1(I.z); r.w = spike1(I.w);
    return r;
}

__global__ __launch_bounds__(256) void lif_scan_kernel(
        const f32x4* __restrict__ x, f32x4* __restrict__ out) {
    const float d = 0.60653065971263342f;     // exp(-0.5)

    int tid   = blockIdx.x * 256 + threadIdx.x;
    int s     = tid & (SEQ4 - 1);             // float4 index within a time slice
    int chunk = tid >> 13;                    // tid / SEQ4 (block-uniform)

    int t0     = chunk * LCHUNK;
    int nwarm  = (chunk == 0) ? 0 : KHALO;    // block-uniform branch
    int idx    = (t0 - nwarm) * SEQ4 + s;

    f32x4 I = (f32x4)(0.0f);

    // Halo warm-up: converge the state; loads only, no stores.
    #pragma unroll 4
    for (int t = 0; t < nwarm; ++t) {
        f32x4 a = x[idx];
        I = d * I + a;
        idx += SEQ4;
    }

    // Main loop: 4-step groups so 4 independent 16B loads are in flight.
    #pragma unroll 1
    for (int g = 0; g < LCHUNK / 4; ++g) {
        f32x4 a0 = x[idx];
        f32x4 a1 = x[idx + 1 * SEQ4];
        f32x4 a2 = x[idx + 2 * SEQ4];
        f32x4 a3 = x[idx + 3 * SEQ4];

        I = d * I + a0;
        __builtin_nontemporal_store(spike4(I), &out[idx]);
        I = d * I + a1;
        __builtin_nontemporal_store(spike4(I), &out[idx + 1 * SEQ4]);
        I = d * I + a2;
        __builtin_nontemporal_store(spike4(I), &out[idx + 2 * SEQ4]);
        I = d * I + a3;
        __builtin_nontemporal_store(spike4(I), &out[idx + 3 * SEQ4]);

        idx += 4 * SEQ4;
    }
}

extern "C" void kernel_launch(void* const* d_in, const int* in_sizes, int n_in,
                              void* d_out, int out_size, void* d_ws, size_t ws_size,
                              hipStream_t stream) {
    const f32x4* x   = (const f32x4*)d_in[0];
    f32x4*       out = (f32x4*)d_out;
    // 16 chunks * 8192 float4-sequences = 131072 threads
    int total_threads = NCHUNK * SEQ4;
    dim3 grid(total_threads / 256), block(256);
    lif_scan_kernel<<<grid, block, 0, stream>>>(x, out);
}

// Round 3
// 244.803 us; speedup vs baseline: 1.0152x; 1.0152x over previous
//
#include <hip/hip_runtime.h>

// AccumulatorLIF: I[t] = exp(-1/2)*I[t-1] + x[t]; out = sigmoid(4*(I-0.5))
// x: (T=1024, B=32, F=1024) fp32. Memory-bound: ~233 MB HBM traffic observed.
//
// Chunked-scan: T split into 16 chunks of 64; each chunk warm-starts 32 steps
// early (decay^32 ~ 1.1e-7 -> absmax ~4e-3 vs threshold 2e-2, verified R2).
//
// R2 lesson: compiler allocated 16 VGPRs and recycled one 16B staging buffer,
// collapsing MLP to 1 load/thread -> 2.3 TB/s latency-bound. This version
// stages 8 independent f32x4 loads in an unrolled array so all 8 (128 B/lane)
// are in flight before the first use.

#define T_DIM   1024
#define B_DIM   32
#define F_DIM   1024
#define LCHUNK  64
#define KHALO   32
#define F4_DIM  (F_DIM / 4)          // 256 float4 per (t,b) row
#define SEQ4    (B_DIM * F4_DIM)     // 8192 float4 per time step
#define NCHUNK  (T_DIM / LCHUNK)     // 16
#define GDEPTH  8                    // loads in flight per thread

typedef float f32x4 __attribute__((ext_vector_type(4)));

__device__ __forceinline__ float spike1(float I) {
    // sigmoid(4*(I-0.5)) = 1 / (1 + exp(-4*(I-0.5)))
    float z = fmaf(-4.0f, I, 2.0f);
    float e = __expf(z);
    return __builtin_amdgcn_rcpf(1.0f + e);
}

__device__ __forceinline__ f32x4 spike4(f32x4 I) {
    f32x4 r;
    r.x = spike1(I.x); r.y = spike1(I.y); r.z = spike1(I.z); r.w = spike1(I.w);
    return r;
}

__global__ __launch_bounds__(256) void lif_scan_kernel(
        const f32x4* __restrict__ x, f32x4* __restrict__ out) {
    const float d = 0.60653065971263342f;     // exp(-0.5)

    int tid   = blockIdx.x * 256 + threadIdx.x;
    int s     = tid & (SEQ4 - 1);             // float4 index within a time slice
    int chunk = tid >> 13;                    // tid / SEQ4 (block-uniform)

    int t0     = chunk * LCHUNK;
    int nwarm  = (chunk == 0) ? 0 : KHALO;    // block-uniform
    int idx    = (t0 - nwarm) * SEQ4 + s;

    f32x4 I = (f32x4)(0.0f);

    // Halo warm-up: 0 or 4 groups of 8 staged loads (no stores).
    #pragma unroll 1
    for (int g = 0; g < nwarm / GDEPTH; ++g) {
        f32x4 a[GDEPTH];
        #pragma unroll
        for (int j = 0; j < GDEPTH; ++j) a[j] = x[idx + j * SEQ4];
        #pragma unroll
        for (int j = 0; j < GDEPTH; ++j) I = d * I + a[j];
        idx += GDEPTH * SEQ4;
    }

    // Main loop: 8 groups of 8. All 8 loads (128 B/lane) issue before any use.
    #pragma unroll 1
    for (int g = 0; g < LCHUNK / GDEPTH; ++g) {
        f32x4 a[GDEPTH];
        #pragma unroll
        for (int j = 0; j < GDEPTH; ++j) a[j] = x[idx + j * SEQ4];
        #pragma unroll
        for (int j = 0; j < GDEPTH; ++j) {
            I = d * I + a[j];
            __builtin_nontemporal_store(spike4(I), &out[idx + j * SEQ4]);
        }
        idx += GDEPTH * SEQ4;
    }
}

extern "C" void kernel_launch(void* const* d_in, const int* in_sizes, int n_in,
                              void* d_out, int out_size, void* d_ws, size_t ws_size,
                              hipStream_t stream) {
    const f32x4* x   = (const f32x4*)d_in[0];
    f32x4*       out = (f32x4*)d_out;
    int total_threads = NCHUNK * SEQ4;        // 131072
    dim3 grid(total_threads / 256), block(256);
    lif_scan_kernel<<<grid, block, 0, stream>>>(x, out);
}

// Round 5
// 237.388 us; speedup vs baseline: 1.0470x; 1.0312x over previous
//
#include <hip/hip_runtime.h>

// AccumulatorLIF: I[t] = exp(-1/2)*I[t-1] + x[t]; out = sigmoid(4*(I-0.5))
// x: (T=1024, B=32, F=1024) fp32. ~230 MB HBM traffic -> memory-bound.
//
// R4 crash post-mortem: KHALO(24) > LCHUNK(16) made chunk 1 start at t=-8 ->
// OOB read. Fix: nwarm = min(t0, KHALO) (0 / 16 / 24 — all multiples of 8).
// Chunk-1 truncation: 7*e^-8 ~ 2.3e-3 < 2e-2 threshold.
//
// Occupancy lever (R3 lesson): 64 chunks -> 2048 blocks = 8 blocks/CU =
// 32 waves/CU; register allocator caps per-thread MLP at ~2 loads, so TLP
// must supply the outstanding misses.

#define T_DIM   1024
#define B_DIM   32
#define F_DIM   1024
#define LCHUNK  16
#define KHALO   24
#define F4_DIM  (F_DIM / 4)          // 256 float4 per (t,b) row
#define SEQ4    (B_DIM * F4_DIM)     // 8192 float4 per time step
#define NCHUNK  (T_DIM / LCHUNK)     // 64
#define GDEPTH  8

typedef float f32x4 __attribute__((ext_vector_type(4)));

__device__ __forceinline__ float spike1(float I) {
    // sigmoid(4*(I-0.5)) = 1 / (1 + exp(-4*(I-0.5)))
    float z = fmaf(-4.0f, I, 2.0f);
    float e = __expf(z);
    return __builtin_amdgcn_rcpf(1.0f + e);
}

__device__ __forceinline__ f32x4 spike4(f32x4 I) {
    f32x4 r;
    r.x = spike1(I.x); r.y = spike1(I.y); r.z = spike1(I.z); r.w = spike1(I.w);
    return r;
}

__global__ __launch_bounds__(256, 8) void lif_scan_kernel(
        const f32x4* __restrict__ x, f32x4* __restrict__ out) {
    const float d = 0.60653065971263342f;     // exp(-0.5)

    int tid   = blockIdx.x * 256 + threadIdx.x;
    int s     = tid & (SEQ4 - 1);             // float4 index within time slice
    int chunk = tid >> 13;                    // block-uniform (32 blocks/chunk)

    int t0    = chunk * LCHUNK;
    int nwarm = (t0 < KHALO) ? t0 : KHALO;    // block-uniform: 0, 16, or 24
    int idx   = (t0 - nwarm) * SEQ4 + s;      // always >= 0

    f32x4 I = (f32x4)(0.0f);

    // Halo warm-up: 0/2/3 groups of 8 staged loads (no stores).
    #pragma unroll 1
    for (int g = 0; g < nwarm / GDEPTH; ++g) {
        f32x4 a[GDEPTH];
        #pragma unroll
        for (int j = 0; j < GDEPTH; ++j) a[j] = x[idx + j * SEQ4];
        #pragma unroll
        for (int j = 0; j < GDEPTH; ++j) I = d * I + a[j];
        idx += GDEPTH * SEQ4;
    }

    // Main: 2 groups of 8 timesteps.
    #pragma unroll 1
    for (int g = 0; g < LCHUNK / GDEPTH; ++g) {
        f32x4 a[GDEPTH];
        #pragma unroll
        for (int j = 0; j < GDEPTH; ++j) a[j] = x[idx + j * SEQ4];
        #pragma unroll
        for (int j = 0; j < GDEPTH; ++j) {
            I = d * I + a[j];
            __builtin_nontemporal_store(spike4(I), &out[idx + j * SEQ4]);
        }
        idx += GDEPTH * SEQ4;
    }
}

extern "C" void kernel_launch(void* const* d_in, const int* in_sizes, int n_in,
                              void* d_out, int out_size, void* d_ws, size_t ws_size,
                              hipStream_t stream) {
    const f32x4* x   = (const f32x4*)d_in[0];
    f32x4*       out = (f32x4*)d_out;
    int total_threads = NCHUNK * SEQ4;        // 524288
    dim3 grid(total_threads / 256), block(256);
    lif_scan_kernel<<<grid, block, 0, stream>>>(x, out);
}